// Round 20
// baseline (391.005 us; speedup 1.0000x reference)
//
#include <hip/hip_runtime.h>
#include <hip/hip_bf16.h>

#define NUM_ENT   30000
#define NUM_ATTR  10000
#define NUM_NODES 40000
#define NUM_TYPES 10
#define HIDDEN    200
#define KPAD      224      // HIDDEN padded for MFMA K (big GEMM) / N (decoder)
#define XP        416      // decoder K: 401 padded to 13*32
#define NPAD2     30208    // NUM_ENT padded to 118*256 (256-col gemm tiles)
#define N_EDGES   600000
#define BATCH     4096
#define XDIM      401      // 2*HIDDEN + 1
#define RRELU_SLOPE 0.22916666666666666f

using bf16x8 = __attribute__((ext_vector_type(8))) short;
using f32x4  = __attribute__((ext_vector_type(4))) float;
typedef __hip_bfloat16 bf16;

__device__ inline float bf2f(ushort u) { return __uint_as_float((unsigned)u << 16); }

// ---------------------------------------------------------------------------
// Fused: block 0 = prep (caps from norm -> scan -> offs+cursor);
// blocks [1, 1+NCVT) = f32->bf16 convert of ent||attr into h0b;
// blocks [1+NCVT, 1+NCVT+KPAD) = build Wb[224][416] (dec_W zero-padded bf16).
// ---------------------------------------------------------------------------
#define NCVT ((NUM_NODES * HIDDEN / 4 + 1023) / 1024)    // 1954
__global__ __launch_bounds__(1024) void k_cvt_prep(const float* __restrict__ ent,
                                                   const float* __restrict__ attr,
                                                   const float* __restrict__ norm,
                                                   const float* __restrict__ dec_W,
                                                   ushort* __restrict__ h0b,
                                                   int* __restrict__ offsets,
                                                   int* __restrict__ cursor,
                                                   bf16* __restrict__ Wb) {
    int bid = blockIdx.x;
    if (bid == 0) {
        __shared__ int part[1024];
        int t = threadIdx.x;
        const int CH = (NUM_ENT + 1023) / 1024;     // 30
        int base = t * CH;
        int caps[CH];
        int s = 0;
        for (int i = 0; i < CH; ++i) {
            int idx = base + i;
            int c = 0;
            if (idx < NUM_ENT) c = (int)(1.0f / norm[idx] + 0.5f);
            caps[i] = c;
            s += c;
        }
        part[t] = s;
        __syncthreads();
        for (int off = 1; off < 1024; off <<= 1) {
            int v = (t >= off) ? part[t - off] : 0;
            __syncthreads();
            part[t] += v;
            __syncthreads();
        }
        int run = (t == 0) ? 0 : part[t - 1];
        for (int i = 0; i < CH; ++i) {
            int idx = base + i;
            if (idx < NUM_ENT) {
                offsets[idx] = run;
                cursor[idx]  = run;
                run += caps[i];
            }
        }
    } else if (bid <= NCVT) {
        int i4 = (bid - 1) * 1024 + threadIdx.x;    // float4 index
        if (i4 >= NUM_NODES * HIDDEN / 4) return;
        int base = i4 * 4;
        const float* src = (base < NUM_ENT * HIDDEN) ? ent + base
                                                     : attr + (base - NUM_ENT * HIDDEN);
        float4 v = *reinterpret_cast<const float4*>(src);
        ushort4 o;
        o.x = __bfloat16_as_ushort(__float2bfloat16(v.x));
        o.y = __bfloat16_as_ushort(__float2bfloat16(v.y));
        o.z = __bfloat16_as_ushort(__float2bfloat16(v.z));
        o.w = __bfloat16_as_ushort(__float2bfloat16(v.w));
        *reinterpret_cast<ushort4*>(h0b + base) = o;
    } else {
        int n = bid - 1 - NCVT;                     // 0..223
        for (int c = threadIdx.x; c < XP; c += 1024) {
            float v = (n < HIDDEN && c < XDIM) ? dec_W[(size_t)n * XDIM + c] : 0.f;
            Wb[(size_t)n * XP + c] = __float2bfloat16(v);
        }
    }
}

// ---------------------------------------------------------------------------
// Bucket edges by destination; store packed (src<<4 | type).
// ---------------------------------------------------------------------------
__global__ void k_place(const int* __restrict__ edst, const int* __restrict__ esrc,
                        const int* __restrict__ etype, int* __restrict__ cursor,
                        int* __restrict__ sorted) {
    int e = blockIdx.x * blockDim.x + threadIdx.x;
    if (e < N_EDGES) {
        int d = edst[e];
        if (d < NUM_ENT) {
            int p = atomicAdd(&cursor[d], 1);
            sorted[p] = (esrc[e] << 4) | etype[e];
        }
    }
}

// ---------------------------------------------------------------------------
// TWO waves per node; sub-wave partials combined via LDS. No atomics.
// ---------------------------------------------------------------------------
__global__ void k_aggregate(const ushort* __restrict__ h0b, const float* __restrict__ w,
                            const int* __restrict__ offsets, const int* __restrict__ cursor,
                            const int* __restrict__ sorted, const float* __restrict__ norm,
                            bf16* __restrict__ S) {
    __shared__ float wl[NUM_TYPES * HIDDEN];    // 8 KB
    __shared__ float part[2][200];
    for (int i = threadIdx.x; i < NUM_TYPES * HIDDEN; i += blockDim.x)
        wl[i] = w[i];
    __syncthreads();

    int wid  = threadIdx.x >> 6;
    int lane = threadIdx.x & 63;
    int ln   = wid >> 1;                        // local node 0/1
    int sub  = wid & 1;                         // sub-wave within node
    int n    = blockIdx.x * 2 + ln;
    bool live = (n < NUM_ENT);
    bool act  = lane < 50;
    int  c    = lane * 4;

    float4 a0 = make_float4(0, 0, 0, 0), a1 = a0, a2 = a0, a3 = a0;
    if (live) {
        int beg = offsets[n], end = cursor[n];
        int mid = beg + ((end - beg + 1) >> 1);
        int lo = sub ? mid : beg;
        int hi = sub ? end : mid;
        int e = lo;
        for (; e + 4 <= hi; e += 4) {
            int r0 = sorted[e + 0], r1 = sorted[e + 1], r2 = sorted[e + 2], r3 = sorted[e + 3];
            if (act) {
                ushort4 h0 = *reinterpret_cast<const ushort4*>(h0b + (size_t)(r0 >> 4) * HIDDEN + c);
                ushort4 h1 = *reinterpret_cast<const ushort4*>(h0b + (size_t)(r1 >> 4) * HIDDEN + c);
                ushort4 h2 = *reinterpret_cast<const ushort4*>(h0b + (size_t)(r2 >> 4) * HIDDEN + c);
                ushort4 h3 = *reinterpret_cast<const ushort4*>(h0b + (size_t)(r3 >> 4) * HIDDEN + c);
                const float* w0 = &wl[(r0 & 15) * HIDDEN + c];
                const float* w1 = &wl[(r1 & 15) * HIDDEN + c];
                const float* w2 = &wl[(r2 & 15) * HIDDEN + c];
                const float* w3 = &wl[(r3 & 15) * HIDDEN + c];
                a0.x += bf2f(h0.x) * w0[0]; a0.y += bf2f(h0.y) * w0[1];
                a0.z += bf2f(h0.z) * w0[2]; a0.w += bf2f(h0.w) * w0[3];
                a1.x += bf2f(h1.x) * w1[0]; a1.y += bf2f(h1.y) * w1[1];
                a1.z += bf2f(h1.z) * w1[2]; a1.w += bf2f(h1.w) * w1[3];
                a2.x += bf2f(h2.x) * w2[0]; a2.y += bf2f(h2.y) * w2[1];
                a2.z += bf2f(h2.z) * w2[2]; a2.w += bf2f(h2.w) * w2[3];
                a3.x += bf2f(h3.x) * w3[0]; a3.y += bf2f(h3.y) * w3[1];
                a3.z += bf2f(h3.z) * w3[2]; a3.w += bf2f(h3.w) * w3[3];
            }
        }
        for (; e < hi; ++e) {
            int r0 = sorted[e];
            if (act) {
                ushort4 h0 = *reinterpret_cast<const ushort4*>(h0b + (size_t)(r0 >> 4) * HIDDEN + c);
                const float* w0 = &wl[(r0 & 15) * HIDDEN + c];
                a0.x += bf2f(h0.x) * w0[0]; a0.y += bf2f(h0.y) * w0[1];
                a0.z += bf2f(h0.z) * w0[2]; a0.w += bf2f(h0.w) * w0[3];
            }
        }
    }
    float4 acc = make_float4(a0.x + a1.x + a2.x + a3.x,
                             a0.y + a1.y + a2.y + a3.y,
                             a0.z + a1.z + a2.z + a3.z,
                             a0.w + a1.w + a2.w + a3.w);
    if (live && sub == 1 && act)
        *reinterpret_cast<float4*>(&part[ln][c]) = acc;
    __syncthreads();

    if (sub == 0) {
        if (!live) {                            // S zero-pad rows (30000..30207)
            if (lane < KPAD / 4) {
                bf16 z4[4] = {};
                *reinterpret_cast<uint2*>(S + (size_t)n * KPAD + lane * 4) =
                    *reinterpret_cast<uint2*>(z4);
            }
        } else if (act) {
            float4 o = *reinterpret_cast<float4*>(&part[ln][c]);
            float nm = norm[n];
            float v0 = (acc.x + o.x) * nm;
            float v1 = (acc.y + o.y) * nm;
            float v2 = (acc.z + o.z) * nm;
            float v3 = (acc.w + o.w) * nm;
            v0 = (v0 >= 0.f) ? v0 : RRELU_SLOPE * v0;
            v1 = (v1 >= 0.f) ? v1 : RRELU_SLOPE * v1;
            v2 = (v2 >= 0.f) ? v2 : RRELU_SLOPE * v2;
            v3 = (v3 >= 0.f) ? v3 : RRELU_SLOPE * v3;
            bf16 t4[4] = {__float2bfloat16(v0), __float2bfloat16(v1),
                          __float2bfloat16(v2), __float2bfloat16(v3)};
            *reinterpret_cast<uint2*>(S + (size_t)n * KPAD + lane * 4) =
                *reinterpret_cast<uint2*>(t4);
        } else if (lane < KPAD / 4) {           // K-pad 200..223 -> zero
            bf16 z4[4] = {};
            *reinterpret_cast<uint2*>(S + (size_t)n * KPAD + lane * 4) =
                *reinterpret_cast<uint2*>(z4);
        }
    }
}

// ---------------------------------------------------------------------------
// FUSED decoder: build 64 X rows in LDS (XOR-swizzled) then MFMA-GEMM them
// against Wb^T with bias+relu -> Y[4096][224]. 64 blocks x 256 thr (4 waves,
// wave = 16 rows x all 14 col-frags). Removes the X global round-trip.
// Swizzle: shorts index ^ ((row&7)<<3) — 16-row fragment reads are 2-way/free.
// ---------------------------------------------------------------------------
__global__ __launch_bounds__(256) void k_dec_fused(const bf16* __restrict__ S,
                                                   const float* __restrict__ rel_emb,
                                                   const float* __restrict__ time_emb,
                                                   const int* __restrict__ batch,
                                                   const bf16* __restrict__ Wbb,
                                                   const float* __restrict__ dec_b,
                                                   bf16* __restrict__ Y) {
    __shared__ short Xs[64 * XP];               // 53,248 B
    int tid = threadIdx.x;
    int blk = blockIdx.x;

    for (int idx = tid; idx < 64 * XP; idx += 256) {
        int r = idx / XP, c = idx - r * XP;
        int m = blk * 64 + r;
        float v;
        if (c < HIDDEN) {
            int e = batch[m * 4 + 0];
            v = tanhf(__bfloat162float(S[(size_t)e * KPAD + c]));
        } else if (c < 2 * HIDDEN) {
            int rl = batch[m * 4 + 1];
            v = rel_emb[(size_t)rl * HIDDEN + (c - HIDDEN)];
        } else if (c == 2 * HIDDEN) {
            v = time_emb[batch[m * 4 + 3] / 24];
        } else {
            v = 0.f;
        }
        Xs[idx ^ ((r & 7) << 3)] = (short)__bfloat16_as_ushort(__float2bfloat16(v));
    }
    __syncthreads();

    int wid  = tid >> 6;
    int lane = tid & 63;
    int rsel = lane & 15;
    int koff = (lane >> 4) * 8;
    int lrow = wid * 16 + rsel;                 // local X row for A-frags
    unsigned sw = (unsigned)(lrow & 7) << 3;

    const short* Wp = reinterpret_cast<const short*>(Wbb);

    f32x4 acc[14] = {};
#pragma unroll
    for (int kt = 0; kt < 13; ++kt) {
        int kbase = kt * 32 + koff;
        bf16x8 a = *reinterpret_cast<const bf16x8*>(&Xs[((unsigned)(lrow * XP + kbase)) ^ sw]);
#pragma unroll
        for (int j = 0; j < 14; ++j) {
            bf16x8 b = *reinterpret_cast<const bf16x8*>(Wp + (size_t)(j * 16 + rsel) * XP + kbase);
            acc[j] = __builtin_amdgcn_mfma_f32_16x16x32_bf16(a, b, acc[j], 0, 0, 0);
        }
    }

    int crow = (lane >> 4) * 4;     // C/D: col=lane&15, row=(lane>>4)*4+r
    int ccol = lane & 15;
    int row0 = blk * 64 + wid * 16;
#pragma unroll
    for (int j = 0; j < 14; ++j) {
        int col = j * 16 + ccol;
        float bias = (col < HIDDEN) ? dec_b[col] : 0.f;
#pragma unroll
        for (int r = 0; r < 4; ++r) {
            int row = row0 + crow + r;
            float v = fmaxf(acc[j][r] + bias, 0.f);
            Y[(size_t)row * KPAD + col] = __float2bfloat16(v);
        }
    }
}

// ---------------------------------------------------------------------------
// out[4096][30000] (f32) = Y(4096x224) . S^T(224x30208pad), bf16 MFMA.
// 256x256 tile, 8 waves, row-band-major, barrier-free per-wave LDS bounce,
// nontemporal stores (R18 config — best measured).
// ---------------------------------------------------------------------------
__global__ __launch_bounds__(512, 2) void k_gemm(const bf16* __restrict__ Yb,
                                                 const bf16* __restrict__ Sb,
                                                 float* __restrict__ out) {
    __shared__ float eb[8][32 * 68];            // 69,632 B: per-wave bounce

    int bid   = blockIdx.x;                 // 0..1887
    int xtile = bid % 118;                  // N tile (FAST -> row-band concurrency)
    int ytile = bid / 118;                  // M tile (slow), 0..15

    int tid  = threadIdx.x;
    int wid  = tid >> 6;                    // 0..7
    int lane = tid & 63;
    int wm = wid >> 2, wn = wid & 3;
    int row0 = ytile * 256 + wm * 128;
    int col0 = xtile * 256 + wn * 64;
    int rsel = lane & 15;
    int koff = (lane >> 4) * 8;

    const short* Yp = reinterpret_cast<const short*>(Yb);
    const short* Sp = reinterpret_cast<const short*>(Sb);

    f32x4 acc[8][4] = {};
#pragma unroll
    for (int kt = 0; kt < 7; ++kt) {
        int kbase = kt * 32 + koff;
        bf16x8 a[8], b[4];
#pragma unroll
        for (int i = 0; i < 8; ++i)
            a[i] = *reinterpret_cast<const bf16x8*>(Yp + (size_t)(row0 + i * 16 + rsel) * KPAD + kbase);
#pragma unroll
        for (int j = 0; j < 4; ++j)
            b[j] = *reinterpret_cast<const bf16x8*>(Sp + (size_t)(col0 + j * 16 + rsel) * KPAD + kbase);
#pragma unroll
        for (int i = 0; i < 8; ++i)
#pragma unroll
            for (int j = 0; j < 4; ++j)
                acc[i][j] = __builtin_amdgcn_mfma_f32_16x16x32_bf16(a[i], b[j], acc[i][j], 0, 0, 0);
    }

    // Barrier-free per-wave epilogue: 4 chunks of 32 rows x 64 cols.
    float* myeb = eb[wid];
    int hi16 = lane >> 4;
    int lo16 = lane & 15;
#pragma unroll
    for (int h = 0; h < 4; ++h) {
#pragma unroll
        for (int ii = 0; ii < 2; ++ii)
#pragma unroll
            for (int j = 0; j < 4; ++j)
#pragma unroll
                for (int r = 0; r < 4; ++r)
                    myeb[(ii * 16 + hi16 * 4 + r) * 68 + j * 16 + lo16] = acc[h * 2 + ii][j][r];
#pragma unroll
        for (int q = 0; q < 8; ++q) {
            int lr = q * 4 + hi16;          // 0..31
            int lc = lo16 * 4;              // 0..60
            f32x4 v = *reinterpret_cast<f32x4*>(&myeb[lr * 68 + lc]);
            int grow = row0 + h * 32 + lr;
            int gcol = col0 + lc;
            if (gcol < NUM_ENT)             // 30000%4==0: all-or-nothing per f32x4
                __builtin_nontemporal_store(v,
                    reinterpret_cast<f32x4*>(&out[(size_t)grow * NUM_ENT + gcol]));
        }
    }
}

// ---------------------------------------------------------------------------
extern "C" void kernel_launch(void* const* d_in, const int* in_sizes, int n_in,
                              void* d_out, int out_size, void* d_ws, size_t ws_size,
                              hipStream_t stream) {
    const float* ent_emb  = (const float*)d_in[0];
    const float* attr_emb = (const float*)d_in[1];
    const float* rel_emb  = (const float*)d_in[2];
    const float* time_emb = (const float*)d_in[3];
    const float* rgcn_w   = (const float*)d_in[4];
    const float* dec_W    = (const float*)d_in[5];
    const float* dec_b    = (const float*)d_in[6];
    const float* norm     = (const float*)d_in[7];
    const int*   esrc     = (const int*)d_in[8];
    const int*   edst     = (const int*)d_in[9];
    const int*   etype    = (const int*)d_in[10];
    const int*   batch    = (const int*)d_in[11];

    char* ws = (char*)d_ws;
    bf16*   S      = (bf16*)ws;                           // 30208*224*2 = 13,533,184 B
    bf16*   Y      = (bf16*)(ws + 13533184);              //  1,835,008 B
    int*    offs   = (int*)(ws + 15368192);               //    120,064 B
    int*    cursor = (int*)(ws + 15488256);               //    120,064 B
    int*    sorted = (int*)(ws + 15608320);               //  2,520,000 B
    bf16*   Wb     = (bf16*)(ws + 18128320);              //    186,368 B (224x416)
    ushort* h0b    = (ushort*)(ws + 18314688);            // 16,000,000 B (40000x200)

    k_cvt_prep<<<1 + NCVT + KPAD, 1024, 0, stream>>>(ent_emb, attr_emb, norm, dec_W,
                                                     h0b, offs, cursor, Wb);
    k_place<<<(N_EDGES + 255) / 256, 256, 0, stream>>>(edst, esrc, etype, cursor, sorted);
    k_aggregate<<<NPAD2 / 2, 256, 0, stream>>>(h0b, rgcn_w, offs, cursor, sorted, norm, S);
    k_dec_fused<<<BATCH / 64, 256, 0, stream>>>(S, rel_emb, time_emb, batch, Wb, dec_b, Y);
    k_gemm<<<118 * 16, 512, 0, stream>>>(Y, S, (float*)d_out);
}

// Round 21
// 343.556 us; speedup vs baseline: 1.1381x; 1.1381x over previous
//
#include <hip/hip_runtime.h>
#include <hip/hip_bf16.h>

#define NUM_ENT   30000
#define NUM_ATTR  10000
#define NUM_NODES 40000
#define NUM_TYPES 10
#define HIDDEN    200
#define KPAD      224      // HIDDEN padded for MFMA K (big GEMM) / N (decoder)
#define XP        416      // decoder K: 401 padded to 13*32
#define NPAD2     30208    // NUM_ENT padded to 118*256 (256-col gemm tiles)
#define N_EDGES   600000
#define BATCH     4096
#define XDIM      401      // 2*HIDDEN + 1
#define RRELU_SLOPE 0.22916666666666666f

using bf16x8 = __attribute__((ext_vector_type(8))) short;
using f32x4  = __attribute__((ext_vector_type(4))) float;
typedef __hip_bfloat16 bf16;

__device__ inline float bf2f(ushort u) { return __uint_as_float((unsigned)u << 16); }

// ---------------------------------------------------------------------------
// Fused: block 0 = prep (caps from norm -> exclusive scan -> offs+cursor);
// blocks 1.. = convert ent||attr (f32) to bf16 h0b[40000][200]. 1024 thr.
// ---------------------------------------------------------------------------
__global__ __launch_bounds__(1024) void k_cvt_prep(const float* __restrict__ ent,
                                                   const float* __restrict__ attr,
                                                   const float* __restrict__ norm,
                                                   ushort* __restrict__ h0b,
                                                   int* __restrict__ offsets,
                                                   int* __restrict__ cursor) {
    if (blockIdx.x == 0) {
        __shared__ int part[1024];
        int t = threadIdx.x;
        const int CH = (NUM_ENT + 1023) / 1024;     // 30
        int base = t * CH;
        int caps[CH];
        int s = 0;
        for (int i = 0; i < CH; ++i) {
            int idx = base + i;
            int c = 0;
            if (idx < NUM_ENT) c = (int)(1.0f / norm[idx] + 0.5f);
            caps[i] = c;
            s += c;
        }
        part[t] = s;
        __syncthreads();
        for (int off = 1; off < 1024; off <<= 1) {
            int v = (t >= off) ? part[t - off] : 0;
            __syncthreads();
            part[t] += v;
            __syncthreads();
        }
        int run = (t == 0) ? 0 : part[t - 1];
        for (int i = 0; i < CH; ++i) {
            int idx = base + i;
            if (idx < NUM_ENT) {
                offsets[idx] = run;
                cursor[idx]  = run;
                run += caps[i];
            }
        }
    } else {
        int i4 = (blockIdx.x - 1) * 1024 + threadIdx.x;  // float4 index
        if (i4 >= NUM_NODES * HIDDEN / 4) return;
        int base = i4 * 4;
        const float* src = (base < NUM_ENT * HIDDEN) ? ent + base
                                                     : attr + (base - NUM_ENT * HIDDEN);
        float4 v = *reinterpret_cast<const float4*>(src);
        ushort4 o;
        o.x = __bfloat16_as_ushort(__float2bfloat16(v.x));
        o.y = __bfloat16_as_ushort(__float2bfloat16(v.y));
        o.z = __bfloat16_as_ushort(__float2bfloat16(v.z));
        o.w = __bfloat16_as_ushort(__float2bfloat16(v.w));
        *reinterpret_cast<ushort4*>(h0b + base) = o;
    }
}

// ---------------------------------------------------------------------------
// Bucket edges by destination; store packed (src<<4 | type).
// ---------------------------------------------------------------------------
__global__ void k_place(const int* __restrict__ edst, const int* __restrict__ esrc,
                        const int* __restrict__ etype, int* __restrict__ cursor,
                        int* __restrict__ sorted) {
    int e = blockIdx.x * blockDim.x + threadIdx.x;
    if (e < N_EDGES) {
        int d = edst[e];
        if (d < NUM_ENT) {
            int p = atomicAdd(&cursor[d], 1);
            sorted[p] = (esrc[e] << 4) | etype[e];
        }
    }
}

// ---------------------------------------------------------------------------
// TWO waves per node; sub-wave partials combined via LDS. No atomics.
// ---------------------------------------------------------------------------
__global__ void k_aggregate(const ushort* __restrict__ h0b, const float* __restrict__ w,
                            const int* __restrict__ offsets, const int* __restrict__ cursor,
                            const int* __restrict__ sorted, const float* __restrict__ norm,
                            bf16* __restrict__ S) {
    __shared__ float wl[NUM_TYPES * HIDDEN];    // 8 KB
    __shared__ float part[2][200];
    for (int i = threadIdx.x; i < NUM_TYPES * HIDDEN; i += blockDim.x)
        wl[i] = w[i];
    __syncthreads();

    int wid  = threadIdx.x >> 6;
    int lane = threadIdx.x & 63;
    int ln   = wid >> 1;                        // local node 0/1
    int sub  = wid & 1;                         // sub-wave within node
    int n    = blockIdx.x * 2 + ln;
    bool live = (n < NUM_ENT);
    bool act  = lane < 50;
    int  c    = lane * 4;

    float4 a0 = make_float4(0, 0, 0, 0), a1 = a0, a2 = a0, a3 = a0;
    if (live) {
        int beg = offsets[n], end = cursor[n];
        int mid = beg + ((end - beg + 1) >> 1);
        int lo = sub ? mid : beg;
        int hi = sub ? end : mid;
        int e = lo;
        for (; e + 4 <= hi; e += 4) {
            int r0 = sorted[e + 0], r1 = sorted[e + 1], r2 = sorted[e + 2], r3 = sorted[e + 3];
            if (act) {
                ushort4 h0 = *reinterpret_cast<const ushort4*>(h0b + (size_t)(r0 >> 4) * HIDDEN + c);
                ushort4 h1 = *reinterpret_cast<const ushort4*>(h0b + (size_t)(r1 >> 4) * HIDDEN + c);
                ushort4 h2 = *reinterpret_cast<const ushort4*>(h0b + (size_t)(r2 >> 4) * HIDDEN + c);
                ushort4 h3 = *reinterpret_cast<const ushort4*>(h0b + (size_t)(r3 >> 4) * HIDDEN + c);
                const float* w0 = &wl[(r0 & 15) * HIDDEN + c];
                const float* w1 = &wl[(r1 & 15) * HIDDEN + c];
                const float* w2 = &wl[(r2 & 15) * HIDDEN + c];
                const float* w3 = &wl[(r3 & 15) * HIDDEN + c];
                a0.x += bf2f(h0.x) * w0[0]; a0.y += bf2f(h0.y) * w0[1];
                a0.z += bf2f(h0.z) * w0[2]; a0.w += bf2f(h0.w) * w0[3];
                a1.x += bf2f(h1.x) * w1[0]; a1.y += bf2f(h1.y) * w1[1];
                a1.z += bf2f(h1.z) * w1[2]; a1.w += bf2f(h1.w) * w1[3];
                a2.x += bf2f(h2.x) * w2[0]; a2.y += bf2f(h2.y) * w2[1];
                a2.z += bf2f(h2.z) * w2[2]; a2.w += bf2f(h2.w) * w2[3];
                a3.x += bf2f(h3.x) * w3[0]; a3.y += bf2f(h3.y) * w3[1];
                a3.z += bf2f(h3.z) * w3[2]; a3.w += bf2f(h3.w) * w3[3];
            }
        }
        for (; e < hi; ++e) {
            int r0 = sorted[e];
            if (act) {
                ushort4 h0 = *reinterpret_cast<const ushort4*>(h0b + (size_t)(r0 >> 4) * HIDDEN + c);
                const float* w0 = &wl[(r0 & 15) * HIDDEN + c];
                a0.x += bf2f(h0.x) * w0[0]; a0.y += bf2f(h0.y) * w0[1];
                a0.z += bf2f(h0.z) * w0[2]; a0.w += bf2f(h0.w) * w0[3];
            }
        }
    }
    float4 acc = make_float4(a0.x + a1.x + a2.x + a3.x,
                             a0.y + a1.y + a2.y + a3.y,
                             a0.z + a1.z + a2.z + a3.z,
                             a0.w + a1.w + a2.w + a3.w);
    if (live && sub == 1 && act)
        *reinterpret_cast<float4*>(&part[ln][c]) = acc;
    __syncthreads();

    if (sub == 0) {
        if (!live) {                            // S zero-pad rows (30000..30207)
            if (lane < KPAD / 4) {
                bf16 z4[4] = {};
                *reinterpret_cast<uint2*>(S + (size_t)n * KPAD + lane * 4) =
                    *reinterpret_cast<uint2*>(z4);
            }
        } else if (act) {
            float4 o = *reinterpret_cast<float4*>(&part[ln][c]);
            float nm = norm[n];
            float v0 = (acc.x + o.x) * nm;
            float v1 = (acc.y + o.y) * nm;
            float v2 = (acc.z + o.z) * nm;
            float v3 = (acc.w + o.w) * nm;
            v0 = (v0 >= 0.f) ? v0 : RRELU_SLOPE * v0;
            v1 = (v1 >= 0.f) ? v1 : RRELU_SLOPE * v1;
            v2 = (v2 >= 0.f) ? v2 : RRELU_SLOPE * v2;
            v3 = (v3 >= 0.f) ? v3 : RRELU_SLOPE * v3;
            bf16 t4[4] = {__float2bfloat16(v0), __float2bfloat16(v1),
                          __float2bfloat16(v2), __float2bfloat16(v3)};
            *reinterpret_cast<uint2*>(S + (size_t)n * KPAD + lane * 4) =
                *reinterpret_cast<uint2*>(t4);
        } else if (lane < KPAD / 4) {           // K-pad 200..223 -> zero
            bf16 z4[4] = {};
            *reinterpret_cast<uint2*>(S + (size_t)n * KPAD + lane * 4) =
                *reinterpret_cast<uint2*>(z4);
        }
    }
}

// ---------------------------------------------------------------------------
// Fused: blocks [0,BATCH) build X rows; blocks [BATCH, BATCH+KPAD) build Wb.
// ---------------------------------------------------------------------------
__global__ void k_build_XW(const bf16* __restrict__ S, const float* __restrict__ rel_emb,
                           const float* __restrict__ time_emb, const float* __restrict__ dec_W,
                           const int* __restrict__ batch, bf16* __restrict__ X,
                           bf16* __restrict__ Wb) {
    int b = blockIdx.x;
    if (b < BATCH) {
        int m = b;
        int e  = batch[m * 4 + 0];
        int rl = batch[m * 4 + 1];
        int tr = batch[m * 4 + 3];
        float tv = time_emb[tr / 24];
        for (int c = threadIdx.x; c < XP; c += 256) {
            float v;
            if (c < HIDDEN) {
                v = tanhf(__bfloat162float(S[(size_t)e * KPAD + c]));
            } else if (c < 2 * HIDDEN) {
                v = rel_emb[(size_t)rl * HIDDEN + (c - HIDDEN)];
            } else if (c == 2 * HIDDEN) {
                v = tv;
            } else {
                v = 0.f;
            }
            X[(size_t)m * XP + c] = __float2bfloat16(v);
        }
    } else {
        int n = b - BATCH;
        for (int c = threadIdx.x; c < XP; c += 256) {
            float v = (n < HIDDEN && c < XDIM) ? dec_W[(size_t)n * XDIM + c] : 0.f;
            Wb[(size_t)n * XP + c] = __float2bfloat16(v);
        }
    }
}

// ---------------------------------------------------------------------------
// Y[4096][224] bf16 = relu( X(4096x416) . Wb^T(416x224) + b ), MFMA 16x16x32.
// ---------------------------------------------------------------------------
__global__ __launch_bounds__(256) void k_dec_gemm(const bf16* __restrict__ Xb,
                                                  const bf16* __restrict__ Wbb,
                                                  const float* __restrict__ dec_b,
                                                  bf16* __restrict__ Y) {
    int wid  = threadIdx.x >> 6;
    int lane = threadIdx.x & 63;
    int row0 = blockIdx.x * 64 + wid * 16;
    int rsel = lane & 15;
    int koff = (lane >> 4) * 8;

    const short* Xp = reinterpret_cast<const short*>(Xb);
    const short* Wp = reinterpret_cast<const short*>(Wbb);

    f32x4 acc[14] = {};
#pragma unroll
    for (int kt = 0; kt < 13; ++kt) {
        int kbase = kt * 32 + koff;
        bf16x8 a = *reinterpret_cast<const bf16x8*>(Xp + (size_t)(row0 + rsel) * XP + kbase);
#pragma unroll
        for (int j = 0; j < 14; ++j) {
            bf16x8 b = *reinterpret_cast<const bf16x8*>(Wp + (size_t)(j * 16 + rsel) * XP + kbase);
            acc[j] = __builtin_amdgcn_mfma_f32_16x16x32_bf16(a, b, acc[j], 0, 0, 0);
        }
    }

    int crow = (lane >> 4) * 4;     // C/D: col=lane&15, row=(lane>>4)*4+r
    int ccol = lane & 15;
#pragma unroll
    for (int j = 0; j < 14; ++j) {
        int col = j * 16 + ccol;
        float bias = (col < HIDDEN) ? dec_b[col] : 0.f;
#pragma unroll
        for (int r = 0; r < 4; ++r) {
            int row = row0 + crow + r;
            float v = fmaxf(acc[j][r] + bias, 0.f);
            Y[(size_t)row * KPAD + col] = __float2bfloat16(v);
        }
    }
}

// ---------------------------------------------------------------------------
// out[4096][30000] (f32) = Y(4096x224) . S^T(224x30208pad), bf16 MFMA.
// 256x256 tile, 8 waves, row-band-major, nt stores, BARRIER-FREE per-wave
// LDS bounce epilogue (R18 config — best measured: 343.8 us).
// ---------------------------------------------------------------------------
__global__ __launch_bounds__(512, 2) void k_gemm(const bf16* __restrict__ Yb,
                                                 const bf16* __restrict__ Sb,
                                                 float* __restrict__ out) {
    __shared__ float eb[8][32 * 68];            // 69,632 B: per-wave bounce

    int bid   = blockIdx.x;                 // 0..1887
    int xtile = bid % 118;                  // N tile (FAST -> row-band concurrency)
    int ytile = bid / 118;                  // M tile (slow), 0..15

    int tid  = threadIdx.x;
    int wid  = tid >> 6;                    // 0..7
    int lane = tid & 63;
    int wm = wid >> 2, wn = wid & 3;
    int row0 = ytile * 256 + wm * 128;
    int col0 = xtile * 256 + wn * 64;
    int rsel = lane & 15;
    int koff = (lane >> 4) * 8;

    const short* Yp = reinterpret_cast<const short*>(Yb);
    const short* Sp = reinterpret_cast<const short*>(Sb);

    f32x4 acc[8][4] = {};
#pragma unroll
    for (int kt = 0; kt < 7; ++kt) {
        int kbase = kt * 32 + koff;
        bf16x8 a[8], b[4];
#pragma unroll
        for (int i = 0; i < 8; ++i)
            a[i] = *reinterpret_cast<const bf16x8*>(Yp + (size_t)(row0 + i * 16 + rsel) * KPAD + kbase);
#pragma unroll
        for (int j = 0; j < 4; ++j)
            b[j] = *reinterpret_cast<const bf16x8*>(Sp + (size_t)(col0 + j * 16 + rsel) * KPAD + kbase);
#pragma unroll
        for (int i = 0; i < 8; ++i)
#pragma unroll
            for (int j = 0; j < 4; ++j)
                acc[i][j] = __builtin_amdgcn_mfma_f32_16x16x32_bf16(a[i], b[j], acc[i][j], 0, 0, 0);
    }

    // Barrier-free per-wave epilogue: 4 chunks of 32 rows x 64 cols.
    float* myeb = eb[wid];
    int hi16 = lane >> 4;
    int lo16 = lane & 15;
#pragma unroll
    for (int h = 0; h < 4; ++h) {
#pragma unroll
        for (int ii = 0; ii < 2; ++ii)
#pragma unroll
            for (int j = 0; j < 4; ++j)
#pragma unroll
                for (int r = 0; r < 4; ++r)
                    myeb[(ii * 16 + hi16 * 4 + r) * 68 + j * 16 + lo16] = acc[h * 2 + ii][j][r];
#pragma unroll
        for (int q = 0; q < 8; ++q) {
            int lr = q * 4 + hi16;          // 0..31
            int lc = lo16 * 4;              // 0..60
            f32x4 v = *reinterpret_cast<f32x4*>(&myeb[lr * 68 + lc]);
            int grow = row0 + h * 32 + lr;
            int gcol = col0 + lc;
            if (gcol < NUM_ENT)             // 30000%4==0: all-or-nothing per f32x4
                __builtin_nontemporal_store(v,
                    reinterpret_cast<f32x4*>(&out[(size_t)grow * NUM_ENT + gcol]));
        }
    }
}

// ---------------------------------------------------------------------------
extern "C" void kernel_launch(void* const* d_in, const int* in_sizes, int n_in,
                              void* d_out, int out_size, void* d_ws, size_t ws_size,
                              hipStream_t stream) {
    const float* ent_emb  = (const float*)d_in[0];
    const float* attr_emb = (const float*)d_in[1];
    const float* rel_emb  = (const float*)d_in[2];
    const float* time_emb = (const float*)d_in[3];
    const float* rgcn_w   = (const float*)d_in[4];
    const float* dec_W    = (const float*)d_in[5];
    const float* dec_b    = (const float*)d_in[6];
    const float* norm     = (const float*)d_in[7];
    const int*   esrc     = (const int*)d_in[8];
    const int*   edst     = (const int*)d_in[9];
    const int*   etype    = (const int*)d_in[10];
    const int*   batch    = (const int*)d_in[11];

    char* ws = (char*)d_ws;
    bf16*   S      = (bf16*)ws;                           // 30208*224*2 = 13,533,184 B
    bf16*   Y      = (bf16*)(ws + 13533184);              //  1,835,008 B
    int*    offs   = (int*)(ws + 15368192);               //    120,064 B
    int*    cursor = (int*)(ws + 15488256);               //    120,064 B
    int*    sorted = (int*)(ws + 15608320);               //  2,520,000 B
    bf16*   X      = (bf16*)(ws + 18128320);              //  3,407,872 B (4096x416)
    bf16*   Wb     = (bf16*)(ws + 21536192);              //    186,368 B (224x416)
    ushort* h0b    = (ushort*)(ws + 21722560);            // 16,000,000 B (40000x200)

    k_cvt_prep<<<1 + (NUM_NODES * HIDDEN / 4 + 1023) / 1024, 1024, 0, stream>>>(
        ent_emb, attr_emb, norm, h0b, offs, cursor);
    k_place<<<(N_EDGES + 255) / 256, 256, 0, stream>>>(edst, esrc, etype, cursor, sorted);
    k_aggregate<<<NPAD2 / 2, 256, 0, stream>>>(h0b, rgcn_w, offs, cursor, sorted, norm, S);
    k_build_XW<<<BATCH + KPAD, 256, 0, stream>>>(S, rel_emb, time_emb, dec_W, batch, X, Wb);
    k_dec_gemm<<<BATCH / 64, 256, 0, stream>>>(X, Wb, dec_b, Y);
    k_gemm<<<118 * 16, 512, 0, stream>>>(Y, S, (float*)d_out);
}